// Round 1
// baseline (422.244 us; speedup 1.0000x reference)
//
#include <hip/hip_runtime.h>

// One 64-lane wave per row of 512 fp32.
// Lane i owns cols [4i,4i+4) and [256+4i,256+4i+4)  -> two float4 loads,
// each fully coalesced (lane i at byte 16*i within the instruction).
// Argmax slices [16,32),[32,48),[48,64),[64,80) each live in 4 consecutive
// lanes; combine with a 2-step shfl_xor butterfly (first-occurrence max).
__global__ __launch_bounds__(256) void bitwise_row_kernel(
        const float* __restrict__ x, float* __restrict__ out, int n_rows) {
    const int lane = threadIdx.x & 63;
    const int wave = threadIdx.x >> 6;
    const int row  = blockIdx.x * 4 + wave;
    if (row >= n_rows) return;

    const float4* __restrict__ xin = (const float4*)(x   + (size_t)row * 512);
    float4*       __restrict__ po  = (float4*)      (out + (size_t)row * 512);

    float4 v = xin[lane];        // cols 4*lane .. 4*lane+3
    float4 w = xin[64 + lane];   // cols 256+4*lane .. +3  (never modified)

    // ---- local first-occurrence argmax over this lane's 4 cols ----
    const int c0 = lane * 4;
    float bv = v.x; int bi = c0;
    if (v.y > bv) { bv = v.y; bi = c0 + 1; }
    if (v.z > bv) { bv = v.z; bi = c0 + 2; }
    if (v.w > bv) { bv = v.w; bi = c0 + 3; }

    // ---- butterfly across groups of 4 lanes (16-col slices) ----
    #pragma unroll
    for (int m = 1; m <= 2; m <<= 1) {
        float ov = __shfl_xor(bv, m, 64);
        int   oi = __shfl_xor(bi, m, 64);
        if (ov > bv || (ov == bv && oi < bi)) { bv = ov; bi = oi; }
    }
    // winners now uniform within each 4-lane group; pull the 4 slices
    const int a_lo = __shfl(bi,  4, 64) - 16;   // cols [16,32) -> lanes 4..7
    const int a_hi = __shfl(bi,  8, 64) - 32;   // cols [32,48) -> lanes 8..11
    const int b_lo = __shfl(bi, 12, 64) - 48;   // cols [48,64) -> lanes 12..15
    const int b_hi = __shfl(bi, 16, 64) - 64;   // cols [64,80) -> lanes 16..19

    // ---- op flags live in lane 0's cols 0..3 ----
    const float f_and = __shfl(v.x, 0, 64);
    const float f_or  = __shfl(v.y, 0, 64);
    const float f_xor = __shfl(v.z, 0, 64);
    const float f_mk  = __shfl(v.w, 0, 64);

    const bool mk   = f_mk  > 0.5f;
    const bool aand = (f_and > 0.5f) & mk;
    const bool aor  = (f_or  > 0.5f) & mk;
    const bool axr  = (f_xor > 0.5f) & mk;

    const int a = a_lo + 16 * a_hi;
    const int b = b_lo + 16 * b_hi;
    int result = 0;
    if (aand) result = a & b;   // later ops override, matching jnp.where order
    if (aor)  result = a | b;
    if (axr)  result = a ^ b;

    if (aand | aor | axr) {
        const int p_lo = 80 + (result & 15);   // in cols [80,96)
        const int p_hi = 96 + (result >> 4);   // in cols [96,112)
        if (c0     == p_lo || c0     == p_hi) v.x += 1.0f;
        if (c0 + 1 == p_lo || c0 + 1 == p_hi) v.y += 1.0f;
        if (c0 + 2 == p_lo || c0 + 2 == p_hi) v.z += 1.0f;
        if (c0 + 3 == p_lo || c0 + 3 == p_hi) v.w += 1.0f;
    }

    po[lane]      = v;
    po[64 + lane] = w;
}

extern "C" void kernel_launch(void* const* d_in, const int* in_sizes, int n_in,
                              void* d_out, int out_size, void* d_ws, size_t ws_size,
                              hipStream_t stream) {
    const float* x   = (const float*)d_in[0];
    float*       out = (float*)d_out;
    const int n_rows = in_sizes[0] / 512;        // 131072
    const int blocks = (n_rows + 3) / 4;         // 4 waves (rows) per 256-thr block
    bitwise_row_kernel<<<blocks, 256, 0, stream>>>(x, out, n_rows);
}

// Round 2
// 411.522 us; speedup vs baseline: 1.0261x; 1.0261x over previous
//
#include <hip/hip_runtime.h>

// One 64-lane wave per 4 rows of 512 fp32 (ROWS_PER_WAVE=4).
// Per row: lane i owns cols [4i,4i+4) and [256+4i,256+4i+4) -> two float4
// loads, each fully coalesced. All 8 loads issue up-front (128 B of MLP per
// thread); untouched second halves store immediately; the 4 rows' shuffle
// chains interleave so ds_permute latency pipelines.
// Argmax slices [16,32),[32,48),[48,64),[64,80) each live in 4 consecutive
// lanes; combine with a 2-step shfl_xor butterfly (first-occurrence max).

typedef float f4 __attribute__((ext_vector_type(4)));

constexpr int RPW = 4;  // rows per wave

__global__ __launch_bounds__(256) void bitwise_row_kernel(
        const float* __restrict__ x, float* __restrict__ out, int n_rows) {
    const int lane = threadIdx.x & 63;
    const int wave = threadIdx.x >> 6;
    const int row0 = (blockIdx.x * 4 + wave) * RPW;
    if (row0 >= n_rows) return;

    const f4* __restrict__ xin = (const f4*)(x   + (size_t)row0 * 512);
    f4*       __restrict__ po  = (f4*)      (out + (size_t)row0 * 512);
    // row j: first-half f4 index j*128 + lane, second-half j*128 + 64 + lane

    f4 v[RPW], w[RPW];
    #pragma unroll
    for (int j = 0; j < RPW; ++j) {
        v[j] = __builtin_nontemporal_load(&xin[j * 128 + lane]);
        w[j] = __builtin_nontemporal_load(&xin[j * 128 + 64 + lane]);
    }

    // untouched second halves: store as soon as their load lands
    #pragma unroll
    for (int j = 0; j < RPW; ++j)
        __builtin_nontemporal_store(w[j], &po[j * 128 + 64 + lane]);

    // ---- local first-occurrence argmax over this lane's 4 cols, per row ----
    const int c0 = lane * 4;
    float bv[RPW]; int bi[RPW];
    #pragma unroll
    for (int j = 0; j < RPW; ++j) {
        float b_ = v[j][0]; int i_ = c0;
        if (v[j][1] > b_) { b_ = v[j][1]; i_ = c0 + 1; }
        if (v[j][2] > b_) { b_ = v[j][2]; i_ = c0 + 2; }
        if (v[j][3] > b_) { b_ = v[j][3]; i_ = c0 + 3; }
        bv[j] = b_; bi[j] = i_;
    }

    // ---- butterfly across groups of 4 lanes; 4 rows interleaved for ILP ----
    #pragma unroll
    for (int m = 1; m <= 2; m <<= 1) {
        float ov[RPW]; int oi[RPW];
        #pragma unroll
        for (int j = 0; j < RPW; ++j) {
            ov[j] = __shfl_xor(bv[j], m, 64);
            oi[j] = __shfl_xor(bi[j], m, 64);
        }
        #pragma unroll
        for (int j = 0; j < RPW; ++j)
            if (ov[j] > bv[j] || (ov[j] == bv[j] && oi[j] < bi[j])) {
                bv[j] = ov[j]; bi[j] = oi[j];
            }
    }

    #pragma unroll
    for (int j = 0; j < RPW; ++j) {
        // winners uniform within each 4-lane group; pull the 4 slices
        const int a_lo = __shfl(bi[j],  4, 64) - 16;   // cols [16,32)
        const int a_hi = __shfl(bi[j],  8, 64) - 32;   // cols [32,48)
        const int b_lo = __shfl(bi[j], 12, 64) - 48;   // cols [48,64)
        const int b_hi = __shfl(bi[j], 16, 64) - 64;   // cols [64,80)

        // op flags live in lane 0's cols 0..3
        const float f_and = __shfl(v[j][0], 0, 64);
        const float f_or  = __shfl(v[j][1], 0, 64);
        const float f_xor = __shfl(v[j][2], 0, 64);
        const float f_mk  = __shfl(v[j][3], 0, 64);

        const bool mk   = f_mk  > 0.5f;
        const bool aand = (f_and > 0.5f) & mk;
        const bool aor  = (f_or  > 0.5f) & mk;
        const bool axr  = (f_xor > 0.5f) & mk;

        const int a = a_lo + 16 * a_hi;
        const int b = b_lo + 16 * b_hi;
        int result = 0;
        if (aand) result = a & b;   // later ops override (jnp.where order)
        if (aor)  result = a | b;
        if (axr)  result = a ^ b;

        if (aand | aor | axr) {
            const int p_lo = 80 + (result & 15);   // in cols [80,96)
            const int p_hi = 96 + (result >> 4);   // in cols [96,112)
            if (c0     == p_lo || c0     == p_hi) v[j][0] += 1.0f;
            if (c0 + 1 == p_lo || c0 + 1 == p_hi) v[j][1] += 1.0f;
            if (c0 + 2 == p_lo || c0 + 2 == p_hi) v[j][2] += 1.0f;
            if (c0 + 3 == p_lo || c0 + 3 == p_hi) v[j][3] += 1.0f;
        }

        __builtin_nontemporal_store(v[j], &po[j * 128 + lane]);
    }
}

extern "C" void kernel_launch(void* const* d_in, const int* in_sizes, int n_in,
                              void* d_out, int out_size, void* d_ws, size_t ws_size,
                              hipStream_t stream) {
    const float* x   = (const float*)d_in[0];
    float*       out = (float*)d_out;
    const int n_rows = in_sizes[0] / 512;              // 131072
    const int rows_per_block = 4 * RPW;                // 4 waves x 4 rows
    const int blocks = (n_rows + rows_per_block - 1) / rows_per_block;  // 8192
    bitwise_row_kernel<<<blocks, 256, 0, stream>>>(x, out, n_rows);
}